// Round 10
// baseline (870.748 us; speedup 1.0000x reference)
//
#include <hip/hip_runtime.h>
#include <float.h>
#include <stdint.h>

#define QB        8                        // queries per block = one per wave
#define NTHREADS  512
#define LQ        2048
#define NDIM      64
#define KSEL      128
#define CHK       512                      // keys per LDS score chunk
#define SSTR      516                      // padded row stride (floats)
#define LDS_BYTES 28800
#define WS_NEEDED (2u * 8388608u * 2u)     // Khi + Klo, bf16 each: 33.6 MB

typedef __attribute__((ext_vector_type(8))) short  s8v;   // 8 bf16 (4 VGPRs)
typedef __attribute__((ext_vector_type(4))) float  f32x4; // MFMA C/D

// Order-preserving map fp32 -> uint32 (monotone increasing)
__device__ __forceinline__ unsigned ordf(float f) {
  unsigned u = __float_as_uint(f);
  return (u & 0x80000000u) ? ~u : (u | 0x80000000u);
}
__device__ __forceinline__ float unordf(unsigned u) {
  unsigned x = (u & 0x80000000u) ? (u & 0x7FFFFFFFu) : ~u;
  return __uint_as_float(x);
}
__device__ __forceinline__ unsigned short f2bf(float f) {  // RNE, no NaN in data
  unsigned u = __float_as_uint(f);
  return (unsigned short)((u + 0x7FFFu + ((u >> 16) & 1u)) >> 16);
}
__device__ __forceinline__ float bf2f(unsigned short h) {
  return __uint_as_float(((unsigned)h) << 16);
}

// ---- prepass: K fp32 -> (Khi, Klo) bf16 split, one-time ----
extern "C" __global__ void __launch_bounds__(256)
convert_k(const float4* __restrict__ K4, ushort4* __restrict__ Khi,
          ushort4* __restrict__ Klo) {
  const int idx = blockIdx.x * 256 + threadIdx.x;   // 0 .. 2097151
  const float4 f = K4[idx];
  ushort4 h, l;
  h.x = f2bf(f.x); l.x = f2bf(f.x - bf2f(h.x));
  h.y = f2bf(f.y); l.y = f2bf(f.y - bf2f(h.y));
  h.z = f2bf(f.z); l.z = f2bf(f.z - bf2f(h.z));
  h.w = f2bf(f.w); l.w = f2bf(f.w - bf2f(h.w));
  Khi[idx] = h;
  Klo[idx] = l;
}

// ---- per-query: exact top-128 select + softmax + PV ----
// Scores in 8 named uint4s (U0..U7); U<i>.{x,y,z,w} <-> key j = i*256+lane*4+{0..3};
// masked/invalid slots are exactly 0 and guarded by (i <= g8).
// outp = base of this query's 64-dim output row.
__device__ __forceinline__ void select_pv(
    uint4 U0, uint4 U1, uint4 U2, uint4 U3,
    uint4 U4, uint4 U5, uint4 U6, uint4 U7,
    const int g8, const int lane,
    int* __restrict__ list, float* __restrict__ wl,
    const float* __restrict__ Vg, float* __restrict__ outp) {
  const float C = 0.18033688011112042f;   // 0.125 * log2(e)
  const unsigned long long ltmask = (1ull << lane) - 1ull;

  // exact 128th-largest: bitwise radix descent with exact-count early exit
  unsigned p = 0;
  int k = KSEL;
  bool exact = false;
#pragma unroll 1
  for (int b = 31; b >= 0; --b) {
    const unsigned T = p | (1u << b);
    int cnt = 0;
#define CNT_G(i, Uv) \
    if (i <= g8) { \
      cnt += (int)__popcll(__ballot(Uv.x >= T)); \
      cnt += (int)__popcll(__ballot(Uv.y >= T)); \
      cnt += (int)__popcll(__ballot(Uv.z >= T)); \
      cnt += (int)__popcll(__ballot(Uv.w >= T)); \
    }
    CNT_G(0, U0) CNT_G(1, U1) CNT_G(2, U2) CNT_G(3, U3)
    CNT_G(4, U4) CNT_G(5, U5) CNT_G(6, U6) CNT_G(7, U7)
#undef CNT_G
    if (cnt >= KSEL) {
      p = T;
      if (cnt == KSEL) { exact = true; break; }  // {u >= T} IS the top-k set
    } else {
      k = KSEL - cnt;
    }
  }
  const unsigned tu   = exact ? (p - 1u) : p;    // collect via (ui > tu)
  const int      krem = exact ? 0 : k;
  // non-exact with p==0 (fewer than KSEL real candidates): unordf(0) = NaN
  // -> wt > 0 is false -> tie path skipped; strict path collects all real.
  const float    wt   = exact ? 0.f : exp2f(unordf(p) * C);

  // strict-greater collection via ballot-prefix positions (no atomics)
  float zacc = 0.f;
  int base = 0;
#define COLL_C(i, uexpr, cidx) { \
    const unsigned ui = (uexpr); \
    const unsigned long long bm = __ballot(ui > tu); \
    if (ui > tu) { \
      const int pos = base + (int)__popcll(bm & ltmask); \
      const float wv = exp2f(unordf(ui) * C); \
      list[pos] = (i << 8) + (lane << 2) + cidx; \
      wl[pos]   = wv; \
      zacc += wv; \
    } \
    base += (int)__popcll(bm); }
#define COLL_G(i, Uv) \
    if (i <= g8) { COLL_C(i, Uv.x, 0) COLL_C(i, Uv.y, 1) COLL_C(i, Uv.z, 2) COLL_C(i, Uv.w, 3) }
  COLL_G(0, U0) COLL_G(1, U1) COLL_G(2, U2) COLL_G(3, U3)
  COLL_G(4, U4) COLL_G(5, U5) COLL_G(6, U6) COLL_G(7, U7)
#undef COLL_G
#undef COLL_C

  int n = base;
  if (wt > 0.f && krem > 0) {
    // ties: take the krem smallest key indices (reference order) via rank
    int carry = 0;
#define TIE_G(i, Uv) \
    if (i <= g8 && carry < krem) { \
      const bool e0 = (Uv.x == tu), e1 = (Uv.y == tu), e2 = (Uv.z == tu), e3 = (Uv.w == tu); \
      const unsigned long long b0 = __ballot(e0), b1 = __ballot(e1); \
      const unsigned long long b2 = __ballot(e2), b3 = __ballot(e3); \
      int r = carry + (int)__popcll(b0 & ltmask) + (int)__popcll(b1 & ltmask) + \
              (int)__popcll(b2 & ltmask) + (int)__popcll(b3 & ltmask); \
      const int jb = (i << 8) + (lane << 2); \
      if (e0) { if (r < krem) { list[base + r] = jb + 0; wl[base + r] = wt; zacc += wt; } ++r; } \
      if (e1) { if (r < krem) { list[base + r] = jb + 1; wl[base + r] = wt; zacc += wt; } ++r; } \
      if (e2) { if (r < krem) { list[base + r] = jb + 2; wl[base + r] = wt; zacc += wt; } ++r; } \
      if (e3) { if (r < krem) { list[base + r] = jb + 3; wl[base + r] = wt; zacc += wt; } ++r; } \
      carry += (int)__popcll(b0) + (int)__popcll(b1) + \
               (int)__popcll(b2) + (int)__popcll(b3); \
    }
    TIE_G(0, U0) TIE_G(1, U1) TIE_G(2, U2) TIE_G(3, U3)
    TIE_G(4, U4) TIE_G(5, U5) TIE_G(6, U6) TIE_G(7, U7)
#undef TIE_G
    n = base + krem;
  }
  float Z = zacc;
#pragma unroll
  for (int off = 1; off < 64; off <<= 1) Z += __shfl_xor(Z, off, 64);
  __threadfence_block();

  // ---- PV gather, 4-wide: group g = lane>>4 handles list entry i+g; each
  // lane loads float4 (4 dims). One load instruction = 4 full V rows (1 KB),
  // 4x fewer loads + address VALU than scalar-per-lane. Cross-group reduce
  // at the end via 2 shfl_xor steps; 16-lane float4 output write.
  const int grp = lane >> 4;           // 0..3
  const int dl4 = (lane & 15) << 2;    // dim offset 0,4,...,60
  float4 acc4 = {0.f, 0.f, 0.f, 0.f};
  int i = 0;
  for (; i + 8 <= n; i += 8) {
    const int   ja = list[i + grp];
    const int   jb = list[i + 4 + grp];
    const float wa = wl[i + grp];
    const float wb = wl[i + 4 + grp];
    const float4 va = *(const float4*)&Vg[(size_t)ja * NDIM + dl4];
    const float4 vb = *(const float4*)&Vg[(size_t)jb * NDIM + dl4];
    acc4.x += wa * va.x + wb * vb.x;
    acc4.y += wa * va.y + wb * vb.y;
    acc4.z += wa * va.z + wb * vb.z;
    acc4.w += wa * va.w + wb * vb.w;
  }
  for (; i < n; i += 4) {              // ragged tail, weight-masked
    const bool  ok = (i + grp) < n;
    const int   j  = ok ? list[i + grp] : 0;
    const float w  = ok ? wl[i + grp]   : 0.f;
    const float4 v = *(const float4*)&Vg[(size_t)j * NDIM + dl4];
    acc4.x += w * v.x;
    acc4.y += w * v.y;
    acc4.z += w * v.z;
    acc4.w += w * v.w;
  }
  acc4.x += __shfl_xor(acc4.x, 16, 64);
  acc4.y += __shfl_xor(acc4.y, 16, 64);
  acc4.z += __shfl_xor(acc4.z, 16, 64);
  acc4.w += __shfl_xor(acc4.w, 16, 64);
  acc4.x += __shfl_xor(acc4.x, 32, 64);
  acc4.y += __shfl_xor(acc4.y, 32, 64);
  acc4.z += __shfl_xor(acc4.z, 32, 64);
  acc4.w += __shfl_xor(acc4.w, 32, 64);
  if (grp == 0) {
    const float rz = 1.f / Z;
    float4 o;
    o.x = acc4.x * rz;
    o.y = acc4.y * rz;
    o.z = acc4.z * rz;
    o.w = acc4.w * rz;
    *(float4*)(outp + dl4) = o;
  }
}

extern "C" __global__ void __launch_bounds__(NTHREADS, 4)
topk_attn_mfma(const float* __restrict__ Qg_, const float* __restrict__ Vg_,
               const unsigned short* __restrict__ Khi_,
               const unsigned short* __restrict__ Klo_,
               float* __restrict__ Out) {
  extern __shared__ char lds[];
  float*          s_chunk = (float*)(lds);                   // [8][516] 16512 B
  unsigned short* qs_hi   = (unsigned short*)(lds + 16512);  // [16][64] 2048 B
  unsigned short* qs_lo   = (unsigned short*)(lds + 18560);  // 2048 B
  int*            lists   = (int*)(lds + 20608);             // [8][128] 4096 B
  float*          wlist   = (float*)(lds + 24704);           // 4096 B
  // total 28800 B

  // ---- bh-per-XCD clustering swizzle (R9: FETCH 267->49 MB, keep) ----
  // id = 8k + x lands on XCD x. Each XCD owns 8 whole (b,h) heads processed
  // sequentially -> per-XCD working set ~1-2 MB fits its 4 MB L2.
  const int id  = blockIdx.x;
  const int xcd = id & 7;
  const int k   = id >> 3;                 // 0..2047
  const int bh  = xcd + ((k >> 8) << 3);   // 0..63, bh % 8 == xcd
  const int qb  = k & 255;                 // 0..255, sequential per bh

  const int q0   = qb * QB;
  const int tid  = threadIdx.x;
  const int lane = tid & 63;
  const int wid  = tid >> 6;               // wave id = query index in block
  const int m16  = lane & 15;
  const int quad = lane >> 4;

  const float* Qg  = Qg_ + ((size_t)(bh * LQ + q0)) * NDIM;
  const float* Vg  = Vg_ + ((size_t)bh) * LQ * NDIM;
  const unsigned short* Khi = Khi_ + ((size_t)bh) * LQ * NDIM;
  const unsigned short* Klo = Klo_ + ((size_t)bh) * LQ * NDIM;

  // ---- stage Q block (8 real rows + 8 zero rows), bf16-split, into LDS ----
#pragma unroll
  for (int e = tid; e < 16 * NDIM; e += NTHREADS) {   // 2 iters
    const int r = e >> 6;
    const float f = (r < QB) ? Qg[e] : 0.f;
    const unsigned short hh = f2bf(f);
    qs_hi[e] = hh;
    qs_lo[e] = f2bf(f - bf2f(hh));
  }
  __syncthreads();

  // ---- A fragments (Q), held in registers for all tiles ----
  const unsigned short* qh = qs_hi + m16 * NDIM + quad * 8;
  const unsigned short* ql = qs_lo + m16 * NDIM + quad * 8;
  const s8v Ah0 = *(const s8v*)qh;
  const s8v Ah1 = *(const s8v*)(qh + 32);
  const s8v Al0 = *(const s8v*)ql;
  const s8v Al1 = *(const s8v*)(ql + 32);

  const int q    = q0 + wid;               // this wave's query
  const int g8   = q >> 8;                 // per-wave valid 256-key groups
  const int qmax = q0 + QB - 1;
  const int nt   = (qmax >> 4) + 1;        // active 16-key tiles
  const int nch  = (qmax >> 9) + 1;        // active 512-key chunks (1..4)

  // produce one 512-key chunk of scores into s_chunk (rows = wave/query)
  auto produce = [&](const int ch) {
#pragma unroll 1
    for (int t = 0; t < 4; ++t) {
      const int jt = (ch << 5) + wid + (t << 3);
      if (jt >= nt) continue;      // wave-uniform
      const int jc  = (jt << 4) + m16;        // global key column
      const int jcl = jc - (ch << 9);         // chunk-local 0..511
      const unsigned short* kh = Khi + (size_t)jc * NDIM + quad * 8;
      const unsigned short* kl = Klo + (size_t)jc * NDIM + quad * 8;
      const s8v Bh0 = *(const s8v*)kh;
      const s8v Bh1 = *(const s8v*)(kh + 32);
      const s8v Bl0 = *(const s8v*)kl;
      const s8v Bl1 = *(const s8v*)(kl + 32);
      f32x4 c = {0.f, 0.f, 0.f, 0.f};
      c = __builtin_amdgcn_mfma_f32_16x16x32_bf16(Ah0, Bh0, c, 0, 0, 0);
      c = __builtin_amdgcn_mfma_f32_16x16x32_bf16(Al0, Bh0, c, 0, 0, 0);
      c = __builtin_amdgcn_mfma_f32_16x16x32_bf16(Ah1, Bh1, c, 0, 0, 0);
      c = __builtin_amdgcn_mfma_f32_16x16x32_bf16(Al1, Bh1, c, 0, 0, 0);
      c = __builtin_amdgcn_mfma_f32_16x16x32_bf16(Ah0, Bl0, c, 0, 0, 0);
      c = __builtin_amdgcn_mfma_f32_16x16x32_bf16(Ah1, Bl1, c, 0, 0, 0);
      // C/D: col=lane&15 (key), row=quad*4+reg (query); rows 8..15 garbage
      if (quad < 2) {
#pragma unroll
        for (int reg = 0; reg < 4; ++reg) {
          const int r = quad * 4 + reg;       // 0..7
          s_chunk[r * SSTR + jcl] = c[reg];
        }
      }
    }
  };

  // named score registers (no runtime-indexed arrays)
  uint4 U0 = make_uint4(0,0,0,0), U1 = make_uint4(0,0,0,0);
  uint4 U2 = make_uint4(0,0,0,0), U3 = make_uint4(0,0,0,0);
  uint4 U4 = make_uint4(0,0,0,0), U5 = make_uint4(0,0,0,0);
  uint4 U6 = make_uint4(0,0,0,0), U7 = make_uint4(0,0,0,0);

  const float4* row4 = (const float4*)(s_chunk + wid * SSTR);
#define CONSUME_HALF(i8, Uv) \
    if (i8 <= g8) { \
      const float4 a = row4[((i8 & 1) << 6) + lane]; \
      const int jb = (i8 << 8) + (lane << 2); \
      Uv.x = (jb + 0 <= q) ? ordf(a.x) : 0u; \
      Uv.y = (jb + 1 <= q) ? ordf(a.y) : 0u; \
      Uv.z = (jb + 2 <= q) ? ordf(a.z) : 0u; \
      Uv.w = (jb + 3 <= q) ? ordf(a.w) : 0u; \
    }

  // ---- chunked QK^T: produce -> barrier -> consume -> barrier ----
  // nch is block-uniform, so the nested ifs + barriers are uniform.
  produce(0);
  __syncthreads();
  CONSUME_HALF(0, U0)
  CONSUME_HALF(1, U1)
  if (nch > 1) {
    __syncthreads();
    produce(1);
    __syncthreads();
    CONSUME_HALF(2, U2)
    CONSUME_HALF(3, U3)
    if (nch > 2) {
      __syncthreads();
      produce(2);
      __syncthreads();
      CONSUME_HALF(4, U4)
      CONSUME_HALF(5, U5)
      if (nch > 3) {
        __syncthreads();
        produce(3);
        __syncthreads();
        CONSUME_HALF(6, U6)
        CONSUME_HALF(7, U7)
      }
    }
  }
#undef CONSUME_HALF

  // ---- per-wave: one query, select + softmax + PV ----
  select_pv(U0, U1, U2, U3, U4, U5, U6, U7, g8, lane,
            lists + wid * KSEL, wlist + wid * KSEL, Vg,
            Out + ((size_t)(bh * LQ + q)) * NDIM);
}

// ================= fallback (round-4 kernel, used if ws too small) =========
#define FB_QB        8
#define FB_LDS_BYTES 73760

extern "C" __global__ void __launch_bounds__(NTHREADS, 4)
topk_attn_fb(const float* __restrict__ Qg_, const float* __restrict__ Kg_,
             const float* __restrict__ Vg_, float* __restrict__ Out) {
  extern __shared__ char lds[];
  float* s_phys = (float*)(lds);
  int*   lists  = (int*)(lds + 65536);
  float* wlist  = (float*)(lds + 69632);
  float* qs     = (float*)(lds + 65536);

  const int id  = blockIdx.x;
  const int xcd = id & 7;
  const int w   = id >> 3;
  const int bh  = w >> 5;
  const int qb  = ((w & 31) << 3) + xcd;

  const int q0   = qb * FB_QB;
  const int tid  = threadIdx.x;
  const int lane = tid & 63;
  const int wid  = tid >> 6;

  const float* Qg = Qg_ + ((size_t)(bh * LQ + q0)) * NDIM;
  const float* Kg = Kg_ + ((size_t)bh) * LQ * NDIM;
  const float* Vg = Vg_ + ((size_t)bh) * LQ * NDIM;

  if (tid < FB_QB * NDIM / 4) ((float4*)qs)[tid] = ((const float4*)Qg)[tid];
  __syncthreads();

  const int tq   = tid >> 8;
  const int tk   = tid & 255;
  const int j0   = tk << 3;
  const int qmax = q0 + FB_QB - 1;
  const bool active = (j0 <= qmax);

  float acc[4][8];
#pragma unroll
  for (int i = 0; i < 4; ++i)
#pragma unroll
    for (int j = 0; j < 8; ++j) acc[i][j] = 0.f;

  if (active) {
    const float4* K4  = (const float4*)(Kg + (size_t)j0 * NDIM);
    const float4* qs4 = (const float4*)(qs + tq * 4 * NDIM);
#pragma unroll 1
    for (int d4 = 0; d4 < 16; ++d4) {
      float4 qv[4];
#pragma unroll
      for (int i = 0; i < 4; ++i) qv[i] = qs4[i * 16 + d4];
#pragma unroll
      for (int g = 0; g < 4; ++g) {
        const float4 k0 = K4[(2 * g + 0) * 16 + d4];
        const float4 k1 = K4[(2 * g + 1) * 16 + d4];
#pragma unroll
        for (int i = 0; i < 4; ++i) {
          acc[i][2 * g + 0] += qv[i].x * k0.x + qv[i].y * k0.y +
                               qv[i].z * k0.z + qv[i].w * k0.w;
          acc[i][2 * g + 1] += qv[i].x * k1.x + qv[i].y * k1.y +
                               qv[i].z * k1.z + qv[i].w * k1.w;
        }
      }
    }
  }
  __syncthreads();

#pragma unroll
  for (int i = 0; i < 4; ++i) {
    const int q = q0 + tq * 4 + i;
    float4* srow4 = (float4*)(s_phys + (tq * 4 + i) * LQ);
    float4 lo, hi;
    lo.x = (j0 + 0 <= q) ? acc[i][0] : -FLT_MAX;
    lo.y = (j0 + 1 <= q) ? acc[i][1] : -FLT_MAX;
    lo.z = (j0 + 2 <= q) ? acc[i][2] : -FLT_MAX;
    lo.w = (j0 + 3 <= q) ? acc[i][3] : -FLT_MAX;
    hi.x = (j0 + 4 <= q) ? acc[i][4] : -FLT_MAX;
    hi.y = (j0 + 5 <= q) ? acc[i][5] : -FLT_MAX;
    hi.z = (j0 + 6 <= q) ? acc[i][6] : -FLT_MAX;
    hi.w = (j0 + 7 <= q) ? acc[i][7] : -FLT_MAX;
    srow4[tk * 2 + 0] = lo;
    srow4[tk * 2 + 1] = hi;
  }
  __syncthreads();

  const float C = 0.18033688011112042f;
  const int qi = wid;
  const int q = q0 + qi;
  const float* srow = s_phys + qi * LQ;
  const float4* srow4 = (const float4*)srow;

  unsigned u[32];
#pragma unroll
  for (int i = 0; i < 8; ++i) {
    const float4 v = srow4[lane + (i << 6)];
    u[4 * i + 0] = ordf(v.x);
    u[4 * i + 1] = ordf(v.y);
    u[4 * i + 2] = ordf(v.z);
    u[4 * i + 3] = ordf(v.w);
  }

  unsigned p = 0;
  int k = KSEL;
#pragma unroll 1
  for (int b = 31; b >= 0; --b) {
    const unsigned T = p | (1u << b);
    int cnt = 0;
#pragma unroll
    for (int i = 0; i < 32; ++i)
      cnt += (int)__popcll(__ballot(u[i] >= T));
    if (cnt >= KSEL) p = T;
    else             k = KSEL - cnt;
  }
  const unsigned tu = p;
  const int krem = k;
  const float wt = exp2f(unordf(tu) * C);

  const unsigned long long ltmask = (1ull << lane) - 1ull;
  float zacc = 0.f;
  int myeq = 0;
  int base = 0;
#pragma unroll
  for (int i = 0; i < 32; ++i) {
    const unsigned ui = u[i];
    const unsigned long long b = __ballot(ui > tu);
    if (ui > tu) {
      const int pos = base + (int)__popcll(b & ltmask);
      const int j = ((i >> 2) << 8) + (lane << 2) + (i & 3);
      const float wv = exp2f(unordf(ui) * C);
      lists[qi * KSEL + pos] = j;
      wlist[qi * KSEL + pos] = wv;
      zacc += wv;
    }
    base += (int)__popcll(b);
    myeq += (ui == tu) ? 1 : 0;
  }
  int n = base;
  if (wt > 0.f) {
    int te = myeq;
#pragma unroll
    for (int off = 1; off < 64; off <<= 1) te += __shfl_xor(te, off, 64);
    if (te == krem) {
#pragma unroll
      for (int i = 0; i < 32; ++i) {
        const unsigned long long b = __ballot(u[i] == tu);
        if (u[i] == tu) {
          const int pos = base + (int)__popcll(b & ltmask);
          const int j = ((i >> 2) << 8) + (lane << 2) + (i & 3);
          lists[qi * KSEL + pos] = j;
          wlist[qi * KSEL + pos] = wt;
          zacc += wt;
        }
        base += (int)__popcll(b);
      }
      n = base;
    } else {
      if (lane == 0) {
        int taken = 0, pos = base;
        for (int j = 0; j < LQ && taken < krem; ++j) {
          if (ordf(srow[j]) == tu) {
            lists[qi * KSEL + pos] = j;
            wlist[qi * KSEL + pos] = wt;
            pos++; taken++;
          }
        }
        zacc += wt * (float)krem;
      }
      n = KSEL;
    }
  }
  float Z = zacc;
#pragma unroll
  for (int off = 1; off < 64; off <<= 1) Z += __shfl_xor(Z, off, 64);
  __threadfence_block();

  float accv = 0.f;
  int i = 0;
  for (; i + 8 <= n; i += 8) {
    const int4   ja = *(const int4*)  &lists[qi * KSEL + i];
    const int4   jb = *(const int4*)  &lists[qi * KSEL + i + 4];
    const float4 wa = *(const float4*)&wlist[qi * KSEL + i];
    const float4 wb = *(const float4*)&wlist[qi * KSEL + i + 4];
    const float v0 = Vg[(size_t)ja.x * NDIM + lane];
    const float v1 = Vg[(size_t)ja.y * NDIM + lane];
    const float v2 = Vg[(size_t)ja.z * NDIM + lane];
    const float v3 = Vg[(size_t)ja.w * NDIM + lane];
    const float v4 = Vg[(size_t)jb.x * NDIM + lane];
    const float v5 = Vg[(size_t)jb.y * NDIM + lane];
    const float v6 = Vg[(size_t)jb.z * NDIM + lane];
    const float v7 = Vg[(size_t)jb.w * NDIM + lane];
    accv += wa.x * v0 + wa.y * v1 + wa.z * v2 + wa.w * v3 +
            wb.x * v4 + wb.y * v5 + wb.z * v6 + wb.w * v7;
  }
  for (; i < n; ++i) {
    const int j = lists[qi * KSEL + i];
    accv += wlist[qi * KSEL + i] * Vg[(size_t)j * NDIM + lane];
  }
  Out[((size_t)(bh * LQ + q)) * NDIM + lane] = accv / Z;
}

extern "C" void kernel_launch(void* const* d_in, const int* in_sizes, int n_in,
                              void* d_out, int out_size, void* d_ws, size_t ws_size,
                              hipStream_t stream) {
  (void)in_sizes; (void)n_in; (void)out_size;
  const float* Q = (const float*)d_in[0];
  const float* K = (const float*)d_in[1];
  const float* V = (const float*)d_in[2];
  float* Out = (float*)d_out;

  if (ws_size >= WS_NEEDED) {
    ushort4* Khi = (ushort4*)d_ws;
    ushort4* Klo = (ushort4*)((char*)d_ws + 8388608u * 2u);
    convert_k<<<dim3(8192), 256, 0, stream>>>((const float4*)K, Khi, Klo);

    (void)hipFuncSetAttribute(reinterpret_cast<const void*>(&topk_attn_mfma),
                              hipFuncAttributeMaxDynamicSharedMemorySize, LDS_BYTES);
    topk_attn_mfma<<<dim3(16384), NTHREADS, LDS_BYTES, stream>>>(
        Q, V, (const unsigned short*)Khi, (const unsigned short*)Klo, Out);
  } else {
    (void)hipFuncSetAttribute(reinterpret_cast<const void*>(&topk_attn_fb),
                              hipFuncAttributeMaxDynamicSharedMemorySize, FB_LDS_BYTES);
    topk_attn_fb<<<dim3(16384), NTHREADS, FB_LDS_BYTES, stream>>>(Q, K, V, Out);
  }
}

// Round 13
// 849.976 us; speedup vs baseline: 1.0244x; 1.0244x over previous
//
#include <hip/hip_runtime.h>
#include <float.h>
#include <stdint.h>

#define QB        16                       // queries per block = TWO per wave
#define NTHREADS  512                      // 8 waves
#define LQ        2048
#define NDIM      64
#define KSEL      128
#define CHK       512                      // keys per LDS score chunk
#define SSTR      516                      // padded row stride (floats)
#define LDS_BYTES 53504
#define WS_NEEDED (2u * 8388608u * 2u)     // Khi + Klo, bf16 each: 33.6 MB

typedef __attribute__((ext_vector_type(8))) short  s8v;   // 8 bf16 (4 VGPRs)
typedef __attribute__((ext_vector_type(4))) float  f32x4; // MFMA C/D

// Order-preserving map fp32 -> uint32 (monotone increasing)
__device__ __forceinline__ unsigned ordf(float f) {
  unsigned u = __float_as_uint(f);
  return (u & 0x80000000u) ? ~u : (u | 0x80000000u);
}
__device__ __forceinline__ float unordf(unsigned u) {
  unsigned x = (u & 0x80000000u) ? (u & 0x7FFFFFFFu) : ~u;
  return __uint_as_float(x);
}
__device__ __forceinline__ unsigned short f2bf(float f) {  // RNE, no NaN in data
  unsigned u = __float_as_uint(f);
  return (unsigned short)((u + 0x7FFFu + ((u >> 16) & 1u)) >> 16);
}
__device__ __forceinline__ float bf2f(unsigned short h) {
  return __uint_as_float(((unsigned)h) << 16);
}

// ---- prepass: K fp32 -> (Khi, Klo) bf16 split, one-time ----
extern "C" __global__ void __launch_bounds__(256)
convert_k(const float4* __restrict__ K4, ushort4* __restrict__ Khi,
          ushort4* __restrict__ Klo) {
  const int idx = blockIdx.x * 256 + threadIdx.x;   // 0 .. 2097151
  const float4 f = K4[idx];
  ushort4 h, l;
  h.x = f2bf(f.x); l.x = f2bf(f.x - bf2f(h.x));
  h.y = f2bf(f.y); l.y = f2bf(f.y - bf2f(h.y));
  h.z = f2bf(f.z); l.z = f2bf(f.z - bf2f(h.z));
  h.w = f2bf(f.w); l.w = f2bf(f.w - bf2f(h.w));
  Khi[idx] = h;
  Klo[idx] = l;
}

// ---- per-query collect + softmax + PV (threshold already known) ----
// Scores in 8 named uint4s; U<i>.{x,y,z,w} <-> key j = i*256+lane*4+{0..3};
// masked/invalid slots are exactly 0 and guarded by (i <= g8).
__device__ __forceinline__ void collect_pv(
    uint4 U0, uint4 U1, uint4 U2, uint4 U3,
    uint4 U4, uint4 U5, uint4 U6, uint4 U7,
    const unsigned p, const int kr, const bool exact,
    const int g8, const int lane,
    int* __restrict__ list, float* __restrict__ wl,
    const float* __restrict__ Vg, float* __restrict__ outp) {
  const float C = 0.18033688011112042f;   // 0.125 * log2(e)
  const unsigned long long ltmask = (1ull << lane) - 1ull;

  const unsigned tu   = exact ? (p - 1u) : p;    // collect via (ui > tu)
  const int      krem = exact ? 0 : kr;
  // non-exact with p==0 (fewer than KSEL real candidates): unordf(0) = NaN
  // -> wt > 0 is false -> tie path skipped; strict path collects all real.
  const float    wt   = exact ? 0.f : exp2f(unordf(p) * C);

  // strict-greater collection via ballot-prefix positions (no atomics)
  float zacc = 0.f;
  int base = 0;
#define COLL_C(i, uexpr, cidx) { \
    const unsigned ui = (uexpr); \
    const unsigned long long bm = __ballot(ui > tu); \
    if (ui > tu) { \
      const int pos = base + (int)__popcll(bm & ltmask); \
      const float wv = exp2f(unordf(ui) * C); \
      list[pos] = (i << 8) + (lane << 2) + cidx; \
      wl[pos]   = wv; \
      zacc += wv; \
    } \
    base += (int)__popcll(bm); }
#define COLL_G(i, Uv) \
    if (i <= g8) { COLL_C(i, Uv.x, 0) COLL_C(i, Uv.y, 1) COLL_C(i, Uv.z, 2) COLL_C(i, Uv.w, 3) }
  COLL_G(0, U0) COLL_G(1, U1) COLL_G(2, U2) COLL_G(3, U3)
  COLL_G(4, U4) COLL_G(5, U5) COLL_G(6, U6) COLL_G(7, U7)
#undef COLL_G
#undef COLL_C

  int n = base;
  if (wt > 0.f && krem > 0) {
    // ties: take the krem smallest key indices (reference order) via rank
    int carry = 0;
#define TIE_G(i, Uv) \
    if (i <= g8 && carry < krem) { \
      const bool e0 = (Uv.x == tu), e1 = (Uv.y == tu), e2 = (Uv.z == tu), e3 = (Uv.w == tu); \
      const unsigned long long b0 = __ballot(e0), b1 = __ballot(e1); \
      const unsigned long long b2 = __ballot(e2), b3 = __ballot(e3); \
      int r = carry + (int)__popcll(b0 & ltmask) + (int)__popcll(b1 & ltmask) + \
              (int)__popcll(b2 & ltmask) + (int)__popcll(b3 & ltmask); \
      const int jb = (i << 8) + (lane << 2); \
      if (e0) { if (r < krem) { list[base + r] = jb + 0; wl[base + r] = wt; zacc += wt; } ++r; } \
      if (e1) { if (r < krem) { list[base + r] = jb + 1; wl[base + r] = wt; zacc += wt; } ++r; } \
      if (e2) { if (r < krem) { list[base + r] = jb + 2; wl[base + r] = wt; zacc += wt; } ++r; } \
      if (e3) { if (r < krem) { list[base + r] = jb + 3; wl[base + r] = wt; zacc += wt; } ++r; } \
      carry += (int)__popcll(b0) + (int)__popcll(b1) + \
               (int)__popcll(b2) + (int)__popcll(b3); \
    }
    TIE_G(0, U0) TIE_G(1, U1) TIE_G(2, U2) TIE_G(3, U3)
    TIE_G(4, U4) TIE_G(5, U5) TIE_G(6, U6) TIE_G(7, U7)
#undef TIE_G
    n = base + krem;
  }
  float Z = zacc;
#pragma unroll
  for (int off = 1; off < 64; off <<= 1) Z += __shfl_xor(Z, off, 64);
  __threadfence_block();

  // PV gather, 4-wide: group g = lane>>4 handles list entry i+g; each lane
  // loads float4 (4 dims). One load instr = 4 full V rows; cross-group
  // reduce via 2 shfl_xor; 16-lane float4 output write.
  const int grp = lane >> 4;           // 0..3
  const int dl4 = (lane & 15) << 2;    // dim offset 0,4,...,60
  float4 acc4 = {0.f, 0.f, 0.f, 0.f};
  int i = 0;
  for (; i + 8 <= n; i += 8) {
    const int   ja = list[i + grp];
    const int   jb = list[i + 4 + grp];
    const float wa = wl[i + grp];
    const float wb = wl[i + 4 + grp];
    const float4 va = *(const float4*)&Vg[(size_t)ja * NDIM + dl4];
    const float4 vb = *(const float4*)&Vg[(size_t)jb * NDIM + dl4];
    acc4.x += wa * va.x + wb * vb.x;
    acc4.y += wa * va.y + wb * vb.y;
    acc4.z += wa * va.z + wb * vb.z;
    acc4.w += wa * va.w + wb * vb.w;
  }
  for (; i < n; i += 4) {              // ragged tail, weight-masked
    const bool  ok = (i + grp) < n;
    const int   j  = ok ? list[i + grp] : 0;
    const float w  = ok ? wl[i + grp]   : 0.f;
    const float4 v = *(const float4*)&Vg[(size_t)j * NDIM + dl4];
    acc4.x += w * v.x;
    acc4.y += w * v.y;
    acc4.z += w * v.z;
    acc4.w += w * v.w;
  }
  acc4.x += __shfl_xor(acc4.x, 16, 64);
  acc4.y += __shfl_xor(acc4.y, 16, 64);
  acc4.z += __shfl_xor(acc4.z, 16, 64);
  acc4.w += __shfl_xor(acc4.w, 16, 64);
  acc4.x += __shfl_xor(acc4.x, 32, 64);
  acc4.y += __shfl_xor(acc4.y, 32, 64);
  acc4.z += __shfl_xor(acc4.z, 32, 64);
  acc4.w += __shfl_xor(acc4.w, 32, 64);
  if (grp == 0) {
    const float rz = 1.f / Z;
    float4 o;
    o.x = acc4.x * rz;
    o.y = acc4.y * rz;
    o.z = acc4.z * rz;
    o.w = acc4.w * rz;
    *(float4*)(outp + dl4) = o;
  }
}

extern "C" __global__ void __launch_bounds__(NTHREADS, 4)
topk_attn_mfma(const float* __restrict__ Qg_, const float* __restrict__ Vg_,
               const unsigned short* __restrict__ Khi_,
               const unsigned short* __restrict__ Klo_,
               float* __restrict__ Out) {
  extern __shared__ char lds[];
  float*          s_chunk = (float*)(lds);                   // [16][516] 33024 B
  unsigned short* qs_hi   = (unsigned short*)(lds + 33024);  // [16][64] 2048 B
  unsigned short* qs_lo   = (unsigned short*)(lds + 35072);  // 2048 B
  int*            lists   = (int*)(lds + 37120);             // [16][128] 8192 B
  float*          wlist   = (float*)(lds + 45312);           // 8192 B
  // total 53504 B (3 blocks LDS-wise; VGPR cap 128 -> 2 blocks resident)

  // ---- bh-per-XCD clustering swizzle (R9: FETCH 267->49 MB, keep) ----
  // grid 8192 = 64 bh x 128 qb. XCD x owns 8 whole heads sequentially.
  const int id  = blockIdx.x;
  const int xcd = id & 7;
  const int k   = id >> 3;                 // 0..1023
  const int bh  = xcd + ((k >> 7) << 3);   // 0..63, bh % 8 == xcd
  const int qb  = k & 127;                 // 0..127, sequential per bh

  const int q0   = qb * QB;
  const int tid  = threadIdx.x;
  const int lane = tid & 63;
  const int wid  = tid >> 6;               // wave id, 0..7
  const int m16  = lane & 15;
  const int quad = lane >> 4;

  const float* Qg  = Qg_ + ((size_t)(bh * LQ + q0)) * NDIM;
  const float* Vg  = Vg_ + ((size_t)bh) * LQ * NDIM;
  const unsigned short* Khi = Khi_ + ((size_t)bh) * LQ * NDIM;
  const unsigned short* Klo = Klo_ + ((size_t)bh) * LQ * NDIM;

  // ---- stage Q block (16 real rows), bf16-split, into LDS ----
#pragma unroll
  for (int e = tid; e < QB * NDIM; e += NTHREADS) {   // 2 iters
    const float f = Qg[e];
    const unsigned short hh = f2bf(f);
    qs_hi[e] = hh;
    qs_lo[e] = f2bf(f - bf2f(hh));
  }
  __syncthreads();

  // ---- A fragments (Q, 16 REAL rows -> full MFMA utilization) ----
  const unsigned short* qh = qs_hi + m16 * NDIM + quad * 8;
  const unsigned short* ql = qs_lo + m16 * NDIM + quad * 8;
  const s8v Ah0 = *(const s8v*)qh;
  const s8v Ah1 = *(const s8v*)(qh + 32);
  const s8v Al0 = *(const s8v*)ql;
  const s8v Al1 = *(const s8v*)(ql + 32);

  // two queries per wave; both share g8 (q0%16==0, wid<8 -> same 256-group)
  const int qa   = q0 + wid;
  const int qbq  = q0 + wid + 8;
  const int g8   = qa >> 8;
  const int qmax = q0 + QB - 1;
  const int nt   = (qmax >> 4) + 1;        // active 16-key tiles (= qb+1)
  const int nch  = (qmax >> 9) + 1;        // active 512-key chunks (1..4)

  // produce one 512-key chunk of scores into s_chunk (rows = query index)
  auto produce = [&](const int ch) {
#pragma unroll 1
    for (int t = 0; t < 4; ++t) {
      const int jt = (ch << 5) + wid + (t << 3);   // 8 waves x 4 tiles = 32
      if (jt >= nt) continue;      // wave-uniform
      const int jc  = (jt << 4) + m16;        // global key column
      const int jcl = jc - (ch << 9);         // chunk-local 0..511
      const unsigned short* kh = Khi + (size_t)jc * NDIM + quad * 8;
      const unsigned short* kl = Klo + (size_t)jc * NDIM + quad * 8;
      const s8v Bh0 = *(const s8v*)kh;
      const s8v Bh1 = *(const s8v*)(kh + 32);
      const s8v Bl0 = *(const s8v*)kl;
      const s8v Bl1 = *(const s8v*)(kl + 32);
      f32x4 c = {0.f, 0.f, 0.f, 0.f};
      c = __builtin_amdgcn_mfma_f32_16x16x32_bf16(Ah0, Bh0, c, 0, 0, 0);
      c = __builtin_amdgcn_mfma_f32_16x16x32_bf16(Al0, Bh0, c, 0, 0, 0);
      c = __builtin_amdgcn_mfma_f32_16x16x32_bf16(Ah1, Bh1, c, 0, 0, 0);
      c = __builtin_amdgcn_mfma_f32_16x16x32_bf16(Al1, Bh1, c, 0, 0, 0);
      c = __builtin_amdgcn_mfma_f32_16x16x32_bf16(Ah0, Bl0, c, 0, 0, 0);
      c = __builtin_amdgcn_mfma_f32_16x16x32_bf16(Ah1, Bl1, c, 0, 0, 0);
      // C/D: col=lane&15 (key), row=quad*4+reg (query 0..15, ALL real)
#pragma unroll
      for (int reg = 0; reg < 4; ++reg) {
        s_chunk[(quad * 4 + reg) * SSTR + jcl] = c[reg];
      }
    }
  };

  // named score registers: U* = query qa, W* = query qbq (rule #20)
  uint4 U0 = make_uint4(0,0,0,0), U1 = make_uint4(0,0,0,0);
  uint4 U2 = make_uint4(0,0,0,0), U3 = make_uint4(0,0,0,0);
  uint4 U4 = make_uint4(0,0,0,0), U5 = make_uint4(0,0,0,0);
  uint4 U6 = make_uint4(0,0,0,0), U7 = make_uint4(0,0,0,0);
  uint4 W0 = make_uint4(0,0,0,0), W1 = make_uint4(0,0,0,0);
  uint4 W2 = make_uint4(0,0,0,0), W3 = make_uint4(0,0,0,0);
  uint4 W4 = make_uint4(0,0,0,0), W5 = make_uint4(0,0,0,0);
  uint4 W6 = make_uint4(0,0,0,0), W7 = make_uint4(0,0,0,0);

  const float4* rowA = (const float4*)(s_chunk + wid * SSTR);
  const float4* rowB = (const float4*)(s_chunk + (wid + 8) * SSTR);
#define CONSUME_HALF(i8, Uv, Wv) \
    if (i8 <= g8) { \
      const float4 a = rowA[((i8 & 1) << 6) + lane]; \
      const float4 bb = rowB[((i8 & 1) << 6) + lane]; \
      const int jb = (i8 << 8) + (lane << 2); \
      Uv.x = (jb + 0 <= qa) ? ordf(a.x) : 0u; \
      Uv.y = (jb + 1 <= qa) ? ordf(a.y) : 0u; \
      Uv.z = (jb + 2 <= qa) ? ordf(a.z) : 0u; \
      Uv.w = (jb + 3 <= qa) ? ordf(a.w) : 0u; \
      Wv.x = (jb + 0 <= qbq) ? ordf(bb.x) : 0u; \
      Wv.y = (jb + 1 <= qbq) ? ordf(bb.y) : 0u; \
      Wv.z = (jb + 2 <= qbq) ? ordf(bb.z) : 0u; \
      Wv.w = (jb + 3 <= qbq) ? ordf(bb.w) : 0u; \
    }

  // ---- chunked QK^T: produce -> barrier -> consume -> barrier ----
  produce(0);
  __syncthreads();
  CONSUME_HALF(0, U0, W0)
  CONSUME_HALF(1, U1, W1)
  if (nch > 1) {
    __syncthreads();
    produce(1);
    __syncthreads();
    CONSUME_HALF(2, U2, W2)
    CONSUME_HALF(3, U3, W3)
    if (nch > 2) {
      __syncthreads();
      produce(2);
      __syncthreads();
      CONSUME_HALF(4, U4, W4)
      CONSUME_HALF(5, U5, W5)
      if (nch > 3) {
        __syncthreads();
        produce(3);
        __syncthreads();
        CONSUME_HALF(6, U6, W6)
        CONSUME_HALF(7, U7, W7)
      }
    }
  }
#undef CONSUME_HALF

  // ---- DUAL radix descent: two independent chains interleaved per wave ----
  unsigned pa = 0, pb = 0;
  int ka = KSEL, kb = KSEL;
  bool ea = false, eb = false;
#define CNT_ONE(i, Uv, T, cnt) \
    if (i <= g8) { \
      cnt += (int)__popcll(__ballot(Uv.x >= T)); \
      cnt += (int)__popcll(__ballot(Uv.y >= T)); \
      cnt += (int)__popcll(__ballot(Uv.z >= T)); \
      cnt += (int)__popcll(__ballot(Uv.w >= T)); \
    }
#pragma unroll 1
  for (int b = 31; b >= 0; --b) {
    const unsigned bit = 1u << b;
    if (!ea) {
      const unsigned T = pa | bit;
      int cnt = 0;
      CNT_ONE(0, U0, T, cnt) CNT_ONE(1, U1, T, cnt)
      CNT_ONE(2, U2, T, cnt) CNT_ONE(3, U3, T, cnt)
      CNT_ONE(4, U4, T, cnt) CNT_ONE(5, U5, T, cnt)
      CNT_ONE(6, U6, T, cnt) CNT_ONE(7, U7, T, cnt)
      if (cnt >= KSEL) { pa = T; if (cnt == KSEL) ea = true; }
      else             ka = KSEL - cnt;
    }
    if (!eb) {
      const unsigned T = pb | bit;
      int cnt = 0;
      CNT_ONE(0, W0, T, cnt) CNT_ONE(1, W1, T, cnt)
      CNT_ONE(2, W2, T, cnt) CNT_ONE(3, W3, T, cnt)
      CNT_ONE(4, W4, T, cnt) CNT_ONE(5, W5, T, cnt)
      CNT_ONE(6, W6, T, cnt) CNT_ONE(7, W7, T, cnt)
      if (cnt >= KSEL) { pb = T; if (cnt == KSEL) eb = true; }
      else             kb = KSEL - cnt;
    }
    if (ea && eb) break;
  }
#undef CNT_ONE

  // ---- per-query collect + softmax + PV ----
  collect_pv(U0, U1, U2, U3, U4, U5, U6, U7, pa, ka, ea, g8, lane,
             lists + wid * KSEL, wlist + wid * KSEL, Vg,
             Out + ((size_t)(bh * LQ + qa)) * NDIM);
  collect_pv(W0, W1, W2, W3, W4, W5, W6, W7, pb, kb, eb, g8, lane,
             lists + (wid + 8) * KSEL, wlist + (wid + 8) * KSEL, Vg,
             Out + ((size_t)(bh * LQ + qbq)) * NDIM);
}

// ================= fallback (round-4 kernel, used if ws too small) =========
#define FB_QB        8
#define FB_LDS_BYTES 73760

extern "C" __global__ void __launch_bounds__(NTHREADS, 4)
topk_attn_fb(const float* __restrict__ Qg_, const float* __restrict__ Kg_,
             const float* __restrict__ Vg_, float* __restrict__ Out) {
  extern __shared__ char lds[];
  float* s_phys = (float*)(lds);
  int*   lists  = (int*)(lds + 65536);
  float* wlist  = (float*)(lds + 69632);
  float* qs     = (float*)(lds + 65536);

  const int id  = blockIdx.x;
  const int xcd = id & 7;
  const int w   = id >> 3;
  const int bh  = w >> 5;
  const int qb  = ((w & 31) << 3) + xcd;

  const int q0   = qb * FB_QB;
  const int tid  = threadIdx.x;
  const int lane = tid & 63;
  const int wid  = tid >> 6;

  const float* Qg = Qg_ + ((size_t)(bh * LQ + q0)) * NDIM;
  const float* Kg = Kg_ + ((size_t)bh) * LQ * NDIM;
  const float* Vg = Vg_ + ((size_t)bh) * LQ * NDIM;

  if (tid < FB_QB * NDIM / 4) ((float4*)qs)[tid] = ((const float4*)Qg)[tid];
  __syncthreads();

  const int tq   = tid >> 8;
  const int tk   = tid & 255;
  const int j0   = tk << 3;
  const int qmax = q0 + FB_QB - 1;
  const bool active = (j0 <= qmax);

  float acc[4][8];
#pragma unroll
  for (int i = 0; i < 4; ++i)
#pragma unroll
    for (int j = 0; j < 8; ++j) acc[i][j] = 0.f;

  if (active) {
    const float4* K4  = (const float4*)(Kg + (size_t)j0 * NDIM);
    const float4* qs4 = (const float4*)(qs + tq * 4 * NDIM);
#pragma unroll 1
    for (int d4 = 0; d4 < 16; ++d4) {
      float4 qv[4];
#pragma unroll
      for (int i = 0; i < 4; ++i) qv[i] = qs4[i * 16 + d4];
#pragma unroll
      for (int g = 0; g < 4; ++g) {
        const float4 k0 = K4[(2 * g + 0) * 16 + d4];
        const float4 k1 = K4[(2 * g + 1) * 16 + d4];
#pragma unroll
        for (int i = 0; i < 4; ++i) {
          acc[i][2 * g + 0] += qv[i].x * k0.x + qv[i].y * k0.y +
                               qv[i].z * k0.z + qv[i].w * k0.w;
          acc[i][2 * g + 1] += qv[i].x * k1.x + qv[i].y * k1.y +
                               qv[i].z * k1.z + qv[i].w * k1.w;
        }
      }
    }
  }
  __syncthreads();

#pragma unroll
  for (int i = 0; i < 4; ++i) {
    const int q = q0 + tq * 4 + i;
    float4* srow4 = (float4*)(s_phys + (tq * 4 + i) * LQ);
    float4 lo, hi;
    lo.x = (j0 + 0 <= q) ? acc[i][0] : -FLT_MAX;
    lo.y = (j0 + 1 <= q) ? acc[i][1] : -FLT_MAX;
    lo.z = (j0 + 2 <= q) ? acc[i][2] : -FLT_MAX;
    lo.w = (j0 + 3 <= q) ? acc[i][3] : -FLT_MAX;
    hi.x = (j0 + 4 <= q) ? acc[i][4] : -FLT_MAX;
    hi.y = (j0 + 5 <= q) ? acc[i][5] : -FLT_MAX;
    hi.z = (j0 + 6 <= q) ? acc[i][6] : -FLT_MAX;
    hi.w = (j0 + 7 <= q) ? acc[i][7] : -FLT_MAX;
    srow4[tk * 2 + 0] = lo;
    srow4[tk * 2 + 1] = hi;
  }
  __syncthreads();

  const float C = 0.18033688011112042f;
  const int qi = wid;
  const int q = q0 + qi;
  const float* srow = s_phys + qi * LQ;
  const float4* srow4 = (const float4*)srow;

  unsigned u[32];
#pragma unroll
  for (int i = 0; i < 8; ++i) {
    const float4 v = srow4[lane + (i << 6)];
    u[4 * i + 0] = ordf(v.x);
    u[4 * i + 1] = ordf(v.y);
    u[4 * i + 2] = ordf(v.z);
    u[4 * i + 3] = ordf(v.w);
  }

  unsigned p = 0;
  int k = KSEL;
#pragma unroll 1
  for (int b = 31; b >= 0; --b) {
    const unsigned T = p | (1u << b);
    int cnt = 0;
#pragma unroll
    for (int i = 0; i < 32; ++i)
      cnt += (int)__popcll(__ballot(u[i] >= T));
    if (cnt >= KSEL) p = T;
    else             k = KSEL - cnt;
  }
  const unsigned tu = p;
  const int krem = k;
  const float wt = exp2f(unordf(tu) * C);

  const unsigned long long ltmask = (1ull << lane) - 1ull;
  float zacc = 0.f;
  int myeq = 0;
  int base = 0;
#pragma unroll
  for (int i = 0; i < 32; ++i) {
    const unsigned ui = u[i];
    const unsigned long long b = __ballot(ui > tu);
    if (ui > tu) {
      const int pos = base + (int)__popcll(b & ltmask);
      const int j = ((i >> 2) << 8) + (lane << 2) + (i & 3);
      const float wv = exp2f(unordf(ui) * C);
      lists[qi * KSEL + pos] = j;
      wlist[qi * KSEL + pos] = wv;
      zacc += wv;
    }
    base += (int)__popcll(b);
    myeq += (ui == tu) ? 1 : 0;
  }
  int n = base;
  if (wt > 0.f) {
    int te = myeq;
#pragma unroll
    for (int off = 1; off < 64; off <<= 1) te += __shfl_xor(te, off, 64);
    if (te == krem) {
#pragma unroll
      for (int i = 0; i < 32; ++i) {
        const unsigned long long b = __ballot(u[i] == tu);
        if (u[i] == tu) {
          const int pos = base + (int)__popcll(b & ltmask);
          const int j = ((i >> 2) << 8) + (lane << 2) + (i & 3);
          lists[qi * KSEL + pos] = j;
          wlist[qi * KSEL + pos] = wt;
          zacc += wt;
        }
        base += (int)__popcll(b);
      }
      n = base;
    } else {
      if (lane == 0) {
        int taken = 0, pos = base;
        for (int j = 0; j < LQ && taken < krem; ++j) {
          if (ordf(srow[j]) == tu) {
            lists[qi * KSEL + pos] = j;
            wlist[qi * KSEL + pos] = wt;
            pos++; taken++;
          }
        }
        zacc += wt * (float)krem;
      }
      n = KSEL;
    }
  }
  float Z = zacc;
#pragma unroll
  for (int off = 1; off < 64; off <<= 1) Z += __shfl_xor(Z, off, 64);
  __threadfence_block();

  float accv = 0.f;
  int i = 0;
  for (; i + 8 <= n; i += 8) {
    const int4   ja = *(const int4*)  &lists[qi * KSEL + i];
    const int4   jb = *(const int4*)  &lists[qi * KSEL + i + 4];
    const float4 wa = *(const float4*)&wlist[qi * KSEL + i];
    const float4 wb = *(const float4*)&wlist[qi * KSEL + i + 4];
    const float v0 = Vg[(size_t)ja.x * NDIM + lane];
    const float v1 = Vg[(size_t)ja.y * NDIM + lane];
    const float v2 = Vg[(size_t)ja.z * NDIM + lane];
    const float v3 = Vg[(size_t)ja.w * NDIM + lane];
    const float v4 = Vg[(size_t)jb.x * NDIM + lane];
    const float v5 = Vg[(size_t)jb.y * NDIM + lane];
    const float v6 = Vg[(size_t)jb.z * NDIM + lane];
    const float v7 = Vg[(size_t)jb.w * NDIM + lane];
    accv += wa.x * v0 + wa.y * v1 + wa.z * v2 + wa.w * v3 +
            wb.x * v4 + wb.y * v5 + wb.z * v6 + wb.w * v7;
  }
  for (; i < n; ++i) {
    const int j = lists[qi * KSEL + i];
    accv += wlist[qi * KSEL + i] * Vg[(size_t)j * NDIM + lane];
  }
  Out[((size_t)(bh * LQ + q)) * NDIM + lane] = accv / Z;
}

extern "C" void kernel_launch(void* const* d_in, const int* in_sizes, int n_in,
                              void* d_out, int out_size, void* d_ws, size_t ws_size,
                              hipStream_t stream) {
  (void)in_sizes; (void)n_in; (void)out_size;
  const float* Q = (const float*)d_in[0];
  const float* K = (const float*)d_in[1];
  const float* V = (const float*)d_in[2];
  float* Out = (float*)d_out;

  if (ws_size >= WS_NEEDED) {
    ushort4* Khi = (ushort4*)d_ws;
    ushort4* Klo = (ushort4*)((char*)d_ws + 8388608u * 2u);
    convert_k<<<dim3(8192), 256, 0, stream>>>((const float4*)K, Khi, Klo);

    (void)hipFuncSetAttribute(reinterpret_cast<const void*>(&topk_attn_mfma),
                              hipFuncAttributeMaxDynamicSharedMemorySize, LDS_BYTES);
    topk_attn_mfma<<<dim3(8192), NTHREADS, LDS_BYTES, stream>>>(
        Q, V, (const unsigned short*)Khi, (const unsigned short*)Klo, Out);
  } else {
    (void)hipFuncSetAttribute(reinterpret_cast<const void*>(&topk_attn_fb),
                              hipFuncAttributeMaxDynamicSharedMemorySize, FB_LDS_BYTES);
    topk_attn_fb<<<dim3(16384), NTHREADS, FB_LDS_BYTES, stream>>>(Q, K, V, Out);
  }
}